// Round 1
// 1870.170 us; speedup vs baseline: 1.6262x; 1.6262x over previous
//
#include <hip/hip_runtime.h>

// LSTM: L=2 layers, B=32, T=256, N=M=1024, gates 4M=4096
// Fused pipelined kernel: 128 blocks (64 per layer), layer 1 lags layer 0 by
// one step. gates = [in_t | h_{t-1}] @ [Wih|Whh]^T + b  (concat K=2048), so no
// separate x-projection GEMM is needed and layers overlap (257 barriered
// iterations instead of 512).

typedef __bf16 bf16x8 __attribute__((ext_vector_type(8)));
typedef float  f32x4  __attribute__((ext_vector_type(4)));
typedef unsigned u32x4 __attribute__((ext_vector_type(4)));

__device__ __forceinline__ unsigned short f2bf(float f) {
    union { float f; unsigned u; } v; v.f = f;
    unsigned u = v.u;
    unsigned r = u + 0x7fffu + ((u >> 16) & 1u);   // RNE
    return (unsigned short)(r >> 16);
}
__device__ __forceinline__ float bf2f(unsigned short b) {
    union { unsigned u; float f; } v; v.u = ((unsigned)b) << 16;
    return v.f;
}
__device__ __forceinline__ float sigmoidf_fast(float x) {
    return 1.0f / (1.0f + __expf(-x));
}
__device__ __forceinline__ float tanhf_fast(float x) {
    return 1.0f - 2.0f / (__expf(2.0f * x) + 1.0f);
}

__global__ void cvt_f32_to_bf16(const float* __restrict__ src,
                                unsigned short* __restrict__ dst, int n4) {
    int i = blockIdx.x * blockDim.x + threadIdx.x;
    int stride = gridDim.x * blockDim.x;
    for (; i < n4; i += stride) {
        float4 v = ((const float4*)src)[i];
        ushort4 o;
        o.x = f2bf(v.x); o.y = f2bf(v.y); o.z = f2bf(v.z); o.w = f2bf(v.w);
        ((ushort4*)dst)[i] = o;
    }
}

// src: (L*4096, 1024) f32 -> dst: (L*4096, 2048) bf16 at column offset `off`
__global__ void cvt_w_concat(const float* __restrict__ src,
                             unsigned short* __restrict__ dst, int off, int n4) {
    int i = blockIdx.x * blockDim.x + threadIdx.x;
    int stride = gridDim.x * blockDim.x;
    for (; i < n4; i += stride) {
        float4 v = ((const float4*)src)[i];
        ushort4 o;
        o.x = f2bf(v.x); o.y = f2bf(v.y); o.z = f2bf(v.z); o.w = f2bf(v.w);
        int row = i >> 8;       // 256 float4 per 1024-col row
        int c4  = i & 255;
        *(ushort4*)&dst[(size_t)row * 2048 + off + c4 * 4] = o;
    }
}

#define TPAD 2056   // hsh row stride in bf16 elems (4112 B, 16B-aligned rows)

// Persistent fused recurrence. Block bid: layer l = bid>>6, m-block = bid&63.
// Per iteration s: layer0 computes t=s (s<256), layer1 computes t=s-1 (s>=1).
// Per-block GEMM: 32 x 64gates x K=2048, 4-way K-split across waves with
// A-frag reuse (each wave: 32 ds_read_b128 + 128 MFMA), partials reduced via
// LDS (gred aliased into hsh). h exchange: agent-scope write-through stores +
// batched sc0 sc1 bypass loads (one vmcnt). Barrier: 128 flag lines, 2 waves
// gather-poll 64 each.
__global__ __launch_bounds__(256, 1) void lstm_fused(
    const unsigned short* __restrict__ Wcat,  // (L,4096,2048) bf16 [Wih|Whh]
    const unsigned short* __restrict__ xbf,   // (B,T,1024) bf16
    unsigned short* __restrict__ seqbf,       // (B,T,1024) bf16 layer0 output
    const unsigned short* __restrict__ h0bf,  // (L,32,1024) bf16 initial h
    unsigned short* __restrict__ hpar,        // (L,2,32,1024) bf16 parity bufs
    const float* __restrict__ c0,             // (L,32,1024) f32 initial c
    const float* __restrict__ bih, const float* __restrict__ bhh,
    float* __restrict__ out, unsigned int* flags)
{
    __shared__ __align__(16) unsigned short hsh[32][TPAD];   // 131584 B
    __shared__ __align__(16) float gfin[32][68];             //   8704 B
    // partial-sum scratch aliased into hsh (used only between sync2..sync4,
    // when all MFMA reads of hsh are done): [wave][half][ct][col n][row pad20]
    float (*gred)[2][4][16][20] = (float (*)[2][4][16][20])&hsh[0][0]; // 40960 B

    const int tid  = threadIdx.x;
    const int lane = tid & 63;
    const int w    = tid >> 6;
    const int l    = blockIdx.x >> 6;
    const int m0   = (blockIdx.x & 63) * 16;
    const int n    = lane & 15;
    const int lk   = (lane >> 4) * 8;
    const int kb   = w * 512;            // this wave's K-slice base

    // ---- persistent weights: wreg[ct*16+kc] = B-frag for col-tile ct, k-step kc
    bf16x8 wreg[64];
    const unsigned short* Wl = Wcat + (size_t)l * 4096 * 2048;
    #pragma unroll
    for (int ct = 0; ct < 4; ct++) {
        int vc = ct * 16 + n;                               // gate-col in block
        size_t jrow = (size_t)((vc & 3) * 1024 + m0 + (vc >> 2));
        #pragma unroll
        for (int kc = 0; kc < 16; kc++)
            wreg[ct * 16 + kc] = *(const bf16x8*)&Wl[jrow * 2048 + kb + kc * 32 + lk];
    }

    // ---- epilogue ownership: thread -> (batch eb, m-pair em,em+1), bias folded
    const int eb = lane >> 1;
    const int q  = lane & 1;
    const int em = m0 + 4 * w + 2 * q;
    float bs0[4], bs1[4];
    #pragma unroll
    for (int g = 0; g < 4; g++) {
        bs0[g] = bih[l * 4096 + g * 1024 + em]     + bhh[l * 4096 + g * 1024 + em];
        bs1[g] = bih[l * 4096 + g * 1024 + em + 1] + bhh[l * 4096 + g * 1024 + em + 1];
    }
    float2 creg = *(const float2*)&c0[(size_t)l * 32768 + eb * 1024 + em];
    float2 hlast = {0.f, 0.f};

    const unsigned short* inb = (l == 0) ? xbf : seqbf;   // (B,T,1024) layout
    const int srow = tid >> 7;           // staging row parity (0/1)
    const int scol = tid & 127;          // *16B within a 2048B row

    #pragma unroll 1
    for (int s = 0; s <= 256; s++) {
        const int  t      = (l == 0) ? s : s - 1;
        const bool active = (l == 0) ? (s < 256) : (s >= 1);

        if (active) {
            const unsigned short* hinb = (t == 0)
                ? h0bf + (size_t)l * 32768
                : hpar + ((size_t)l * 2 + ((t - 1) & 1)) * 32768;

            // ---- batched cache-bypass staging: 32 loads, ONE waitcnt
            u32x4 hv[32];
            #pragma unroll
            for (int si = 0; si < 16; si++) {            // in_t half (K 0..1023)
                int row = 2 * si + srow;
                const void* ap = (const char*)inb
                    + ((size_t)row * 256 + t) * 2048 + scol * 16;
                asm volatile("global_load_dwordx4 %0, %1, off sc0 sc1"
                             : "=v"(hv[si]) : "v"(ap) : "memory");
            }
            #pragma unroll
            for (int si = 0; si < 16; si++) {            // h half (K 1024..2047)
                int row = 2 * si + srow;
                const void* ap = (const char*)hinb + (size_t)row * 2048 + scol * 16;
                asm volatile("global_load_dwordx4 %0, %1, off sc0 sc1"
                             : "=v"(hv[16 + si]) : "v"(ap) : "memory");
            }
            asm volatile("s_waitcnt vmcnt(0)" ::: "memory");
            #pragma unroll
            for (int si = 0; si < 16; si++) {
                int row = 2 * si + srow;
                *(u32x4*)&hsh[row][scol * 8]        = hv[si];
                *(u32x4*)&hsh[row][1024 + scol * 8] = hv[16 + si];
            }
            __syncthreads();   // sync1: tile staged

            // ---- K-sliced GEMM: wave w covers K [kb, kb+512), all 64 cols
            f32x4 acc0[4] = {};   // batches 0..15, col-tiles 0..3
            f32x4 acc1[4] = {};   // batches 16..31
            #pragma unroll
            for (int kc = 0; kc < 16; kc++) {
                bf16x8 a0 = *(const bf16x8*)&hsh[n][kb + kc * 32 + lk];
                bf16x8 a1 = *(const bf16x8*)&hsh[16 + n][kb + kc * 32 + lk];
                #pragma unroll
                for (int ct = 0; ct < 4; ct++) {
                    acc0[ct] = __builtin_amdgcn_mfma_f32_16x16x32_bf16(
                        a0, wreg[ct * 16 + kc], acc0[ct], 0, 0, 0);
                    acc1[ct] = __builtin_amdgcn_mfma_f32_16x16x32_bf16(
                        a1, wreg[ct * 16 + kc], acc1[ct], 0, 0, 0);
                }
            }
            __syncthreads();   // sync2: all hsh reads done, gred may alias

            // ---- write K-partials (C/D: col=n, rows r0..r0+3)
            {
                int r0 = (lane >> 4) * 4;
                #pragma unroll
                for (int ct = 0; ct < 4; ct++) {
                    *(f32x4*)&gred[w][0][ct][n][r0] = acc0[ct];
                    *(f32x4*)&gred[w][1][ct][n][r0] = acc1[ct];
                }
            }
            __syncthreads();   // sync3: partials visible

            // ---- reduce 4 K-partials -> gfin[batch][gatecol]
            #pragma unroll
            for (int i = 0; i < 2; i++) {
                int u   = tid * 2 + i;
                int un  = u & 15, uct = (u >> 4) & 3;
                int uh  = (u >> 6) & 1, urq = (u >> 7) & 3;
                f32x4 p0 = *(const f32x4*)&gred[0][uh][uct][un][urq * 4];
                f32x4 p1 = *(const f32x4*)&gred[1][uh][uct][un][urq * 4];
                f32x4 p2 = *(const f32x4*)&gred[2][uh][uct][un][urq * 4];
                f32x4 p3 = *(const f32x4*)&gred[3][uh][uct][un][urq * 4];
                f32x4 sm = (p0 + p1) + (p2 + p3);
                int col = uct * 16 + un;
                int rowb = uh * 16 + urq * 4;
                #pragma unroll
                for (int j = 0; j < 4; j++)
                    gfin[rowb + j][col] = sm[j];
            }
            __syncthreads();   // sync4: gates final

            // ---- epilogue: thread (eb,q) -> gate cols [16w+8q, +8)
            f32x4 ga = *(const f32x4*)&gfin[eb][16 * w + 8 * q];
            f32x4 gb = *(const f32x4*)&gfin[eb][16 * w + 8 * q + 4];

            float gi0 = ga[0] + bs0[0], gf0 = ga[1] + bs0[1];
            float gg0 = ga[2] + bs0[2], go0 = ga[3] + bs0[3];
            float gi1 = gb[0] + bs1[0], gf1 = gb[1] + bs1[1];
            float gg1 = gb[2] + bs1[2], go1 = gb[3] + bs1[3];

            float c0n = sigmoidf_fast(gf0) * creg.x + sigmoidf_fast(gi0) * tanhf_fast(gg0);
            float c1n = sigmoidf_fast(gf1) * creg.y + sigmoidf_fast(gi1) * tanhf_fast(gg1);
            float h0v = sigmoidf_fast(go0) * tanhf_fast(c0n);
            float h1v = sigmoidf_fast(go1) * tanhf_fast(c1n);
            creg.x = c0n; creg.y = c1n;
            hlast.x = h0v; hlast.y = h1v;

            unsigned hp = (unsigned)f2bf(h0v) | ((unsigned)f2bf(h1v) << 16);
            __hip_atomic_store(
                (unsigned*)&hpar[((size_t)l * 2 + (t & 1)) * 32768 + eb * 1024 + em],
                hp, __ATOMIC_RELAXED, __HIP_MEMORY_SCOPE_AGENT);
            if (l == 0) {
                __hip_atomic_store(
                    (unsigned*)&seqbf[((size_t)eb * 256 + t) * 1024 + em],
                    hp, __ATOMIC_RELAXED, __HIP_MEMORY_SCOPE_AGENT);
            } else {
                float2 hv2 = {h0v, h1v};
                *(float2*)&out[((size_t)eb * 256 + t) * 1024 + em] = hv2;
            }
        }

        // ---- distributed barrier over all 128 blocks
        asm volatile("s_waitcnt vmcnt(0)" ::: "memory");
        __syncthreads();
        if (tid < 128) {
            const unsigned tgt = (unsigned)(s + 1);
            if (tid == 0)
                __hip_atomic_store(flags + (size_t)blockIdx.x * 32, tgt,
                                   __ATOMIC_RELAXED, __HIP_MEMORY_SCOPE_AGENT);
            const unsigned* fp = flags + (size_t)tid * 32;
            while (true) {
                unsigned v = __hip_atomic_load(fp, __ATOMIC_RELAXED,
                                               __HIP_MEMORY_SCOPE_AGENT);
                if (__all((int)(v >= tgt))) break;
                __builtin_amdgcn_s_sleep(1);
            }
        }
        __syncthreads();
    }

    // ---- final states
    float* hF = out + (size_t)8192 * 1024 + (size_t)l * 32768;
    float* cF = out + (size_t)8192 * 1024 + 65536 + (size_t)l * 32768;
    float2 hf2 = {hlast.x, hlast.y};
    *(float2*)&hF[eb * 1024 + em] = hf2;
    float2 cf2 = {creg.x, creg.y};
    *(float2*)&cF[eb * 1024 + em] = cf2;
}

extern "C" void kernel_launch(void* const* d_in, const int* in_sizes, int n_in,
                              void* d_out, int out_size, void* d_ws, size_t ws_size,
                              hipStream_t stream)
{
    const float* x   = (const float*)d_in[0];
    const float* h0  = (const float*)d_in[1];
    const float* c0  = (const float*)d_in[2];
    const float* Wih = (const float*)d_in[3];
    const float* Whh = (const float*)d_in[4];
    const float* bih = (const float*)d_in[5];
    const float* bhh = (const float*)d_in[6];
    float* out = (float*)d_out;

    char* p = (char*)d_ws;
    unsigned short* xbf   = (unsigned short*)p; p += (size_t)8192 * 1024 * 2;      // 16 MB
    unsigned short* seqbf = (unsigned short*)p; p += (size_t)8192 * 1024 * 2;      // 16 MB
    unsigned short* Wcat  = (unsigned short*)p; p += (size_t)2 * 4096 * 2048 * 2;  // 32 MB
    unsigned short* hbfA  = (unsigned short*)p; p += (size_t)2 * 32 * 1024 * 2;    // 128 KB
    unsigned short* hpar  = (unsigned short*)p; p += (size_t)2 * 2 * 32 * 1024 * 2;// 256 KB
    unsigned int*   flags = (unsigned int*)p;   p += 128 * 128;                    // 16 KB

    hipMemsetAsync(flags, 0, 128 * 128, stream);
    cvt_f32_to_bf16<<<1024, 256, 0, stream>>>(x,  xbf,  8192 * 1024 / 4);
    cvt_f32_to_bf16<<<64,   256, 0, stream>>>(h0, hbfA, 2 * 32 * 1024 / 4);
    cvt_w_concat<<<1024, 256, 0, stream>>>(Wih, Wcat, 0,    2 * 4096 * 256);
    cvt_w_concat<<<1024, 256, 0, stream>>>(Whh, Wcat, 1024, 2 * 4096 * 256);

    lstm_fused<<<128, 256, 0, stream>>>(Wcat, xbf, seqbf, hbfA, hpar,
                                        c0, bih, bhh, out, flags);
}